// Round 1
// baseline (298.219 us; speedup 1.0000x reference)
//
#include <hip/hip_runtime.h>
#include <hip/hip_bf16.h>

#define M_TOT 32768
#define DDIM  1024
#define ODIM  768
#define LN_EPS 1e-5f

#define BM 64
#define BN 384
#define BK 32
#define NTHR 512

typedef __attribute__((__ext_vector_type__(8))) short bf16x8;
typedef __attribute__((__ext_vector_type__(4))) float f32x4;

__device__ __forceinline__ unsigned short f2bf(float f) {
  union { __hip_bfloat16 h; unsigned short u; } cv;
  cv.h = __float2bfloat16(f);
  return cv.u;
}

__device__ __forceinline__ float silu_f(float v) {
  return v / (1.f + __expf(-v));
}

__global__ void wconv_kernel(const float4* __restrict__ Wf, ushort4* __restrict__ Wb, int n4) {
  int i = blockIdx.x * blockDim.x + threadIdx.x;
  if (i >= n4) return;
  float4 v = Wf[i];
  ushort4 o;
  o.x = f2bf(v.x); o.y = f2bf(v.y); o.z = f2bf(v.z); o.w = f2bf(v.w);
  Wb[i] = o;
}

template <bool USE_WB>
__global__ __launch_bounds__(NTHR)
void fused_kernel(const float* __restrict__ x,
                  const float* __restrict__ lnw,
                  const float* __restrict__ lnb,
                  const float* __restrict__ Wf,
                  const __hip_bfloat16* __restrict__ Wb,
                  const float* __restrict__ bias,
                  float* __restrict__ out)
{
  extern __shared__ char smem[];
  char* AsBase = smem;                 // [2][64][32] bf16 : 8192 B
  char* BsBase = smem + 8192;          // [2][384][32] bf16 : 49152 B
  float* smean = (float*)(smem + 8192 + 49152);
  float* srstd = smean + BM;

  const int tid = threadIdx.x;
  // XCD-aware swizzle: 1024 blocks, 8 XCDs, bijective (1024 % 8 == 0)
  const int wg  = blockIdx.x;
  const int swz = ((wg & 7) << 7) + (wg >> 3);
  const int mt  = swz & 511;
  const int nt  = swz >> 9;
  const int m0  = mt * BM;
  const int n0  = nt * BN;

  // ---------- pass 0: per-row LayerNorm stats (8 threads per row) ----------
  {
    const int row = tid >> 3;
    const int sub = tid & 7;
    const float4* xr = (const float4*)(x + (size_t)(m0 + row) * DDIM);
    float s = 0.f, ss = 0.f;
#pragma unroll 4
    for (int j = 0; j < 32; ++j) {
      float4 v = xr[sub + (j << 3)];
      s  += v.x + v.y + v.z + v.w;
      ss += v.x * v.x + v.y * v.y + v.z * v.z + v.w * v.w;
    }
#pragma unroll
    for (int off = 1; off < 8; off <<= 1) {
      s  += __shfl_xor(s, off);
      ss += __shfl_xor(ss, off);
    }
    if (sub == 0) {
      float mean = s * (1.f / 1024.f);
      float var  = ss * (1.f / 1024.f) - mean * mean;
      smean[row] = mean;
      srstd[row] = rsqrtf(var + LN_EPS);
    }
  }
  __syncthreads();

  // ---------- staging indices ----------
  const int arow  = tid >> 3;          // 0..63
  const int acol4 = tid & 7;           // float4 index within 32-col K-slab
  const int aOff  = (m0 + arow) * DDIM + (acol4 << 2);
  const int aDstOff = (arow << 6) + ((((acol4 >> 1) ^ ((arow >> 2) & 3)) << 4)) + ((acol4 & 1) << 3);
  const float aMean = smean[arow];
  const float aRstd = srstd[arow];

  int bOff[3], bDst[3];
  int bOffF[6], bDstF[6];
  if constexpr (USE_WB) {
#pragma unroll
    for (int c = 0; c < 3; ++c) {
      int idx = tid + (c << 9);
      int r = idx >> 2, kb = idx & 3;
      bOff[c] = (n0 + r) * DDIM + (kb << 3);
      bDst[c] = (r << 6) + ((kb ^ ((r >> 2) & 3)) << 4);
    }
  } else {
#pragma unroll
    for (int c = 0; c < 6; ++c) {
      int idx = tid + (c << 9);
      int r = idx >> 3, c4 = idx & 7;
      bOffF[c] = (n0 + r) * DDIM + (c4 << 2);
      bDstF[c] = (r << 6) + ((((c4 >> 1) ^ ((r >> 2) & 3)) << 4)) + ((c4 & 1) << 3);
    }
  }

  // ---------- MFMA fragment read offsets (swizzled) ----------
  const int lane = tid & 63;
  const int wid  = tid >> 6;           // 8 waves: 1M x 8N, 48 cols each
  const int lr   = lane & 15;
  const int lq   = lane >> 4;
  const int kswz = (lq ^ ((lr >> 2) & 3)) << 4;
  int aRd[4], bRd[3];
#pragma unroll
  for (int i = 0; i < 4; ++i) aRd[i] = (((i << 4) + lr) << 6) + kswz;
#pragma unroll
  for (int j = 0; j < 3; ++j) bRd[j] = ((wid * 48 + (j << 4) + lr) << 6) + kswz;

  float4 aReg, lwReg, lbReg;
  int4 bReg[3];
  float4 bRegF[6];

  auto loadTile = [&](int tt) {
    const int k0 = tt * BK;
    aReg  = *(const float4*)(x + aOff + k0);
    lwReg = *(const float4*)(lnw + (acol4 << 2) + k0);
    lbReg = *(const float4*)(lnb + (acol4 << 2) + k0);
    if constexpr (USE_WB) {
#pragma unroll
      for (int c = 0; c < 3; ++c)
        bReg[c] = *(const int4*)((const unsigned short*)Wb + bOff[c] + k0);
    } else {
#pragma unroll
      for (int c = 0; c < 6; ++c)
        bRegF[c] = *(const float4*)(Wf + bOffF[c] + k0);
    }
  };

  auto storeTile = [&](int buf) {
    float h0 = (aReg.x - aMean) * aRstd * lwReg.x + lbReg.x;
    float h1 = (aReg.y - aMean) * aRstd * lwReg.y + lbReg.y;
    float h2 = (aReg.z - aMean) * aRstd * lwReg.z + lbReg.z;
    float h3 = (aReg.w - aMean) * aRstd * lwReg.w + lbReg.w;
    h0 = silu_f(h0); h1 = silu_f(h1); h2 = silu_f(h2); h3 = silu_f(h3);
    ushort4 ap; ap.x = f2bf(h0); ap.y = f2bf(h1); ap.z = f2bf(h2); ap.w = f2bf(h3);
    *(ushort4*)(AsBase + buf * 4096 + aDstOff) = ap;
    if constexpr (USE_WB) {
#pragma unroll
      for (int c = 0; c < 3; ++c)
        *(int4*)(BsBase + buf * 24576 + bDst[c]) = bReg[c];
    } else {
#pragma unroll
      for (int c = 0; c < 6; ++c) {
        float4 w = bRegF[c];
        ushort4 bp; bp.x = f2bf(w.x); bp.y = f2bf(w.y); bp.z = f2bf(w.z); bp.w = f2bf(w.w);
        *(ushort4*)(BsBase + buf * 24576 + bDstF[c]) = bp;
      }
    }
  };

  f32x4 acc[4][3];
#pragma unroll
  for (int i = 0; i < 4; ++i)
#pragma unroll
    for (int j = 0; j < 3; ++j)
      acc[i][j] = (f32x4){0.f, 0.f, 0.f, 0.f};

  loadTile(0);
  storeTile(0);
  __syncthreads();

#pragma unroll 2
  for (int t = 0; t < 32; ++t) {
    const int cur = t & 1;
    if (t < 31) loadTile(t + 1);           // issue next-tile global loads early
    const char* aB = AsBase + cur * 4096;
    const char* bB = BsBase + cur * 24576;
    bf16x8 af[4], bfr[3];
#pragma unroll
    for (int i = 0; i < 4; ++i) af[i] = *(const bf16x8*)(aB + aRd[i]);
#pragma unroll
    for (int j = 0; j < 3; ++j) bfr[j] = *(const bf16x8*)(bB + bRd[j]);
#pragma unroll
    for (int i = 0; i < 4; ++i)
#pragma unroll
      for (int j = 0; j < 3; ++j)
        acc[i][j] = __builtin_amdgcn_mfma_f32_16x16x32_bf16(af[i], bfr[j], acc[i][j], 0, 0, 0);
    if (t < 31) storeTile(cur ^ 1);        // convert + ds_write after MFMA
    __syncthreads();
  }

  // ---------- epilogue: bias + patch rearrange + scattered store ----------
  // y[m][o] -> out[b][c][h*16+ph][w*16+pw]; m=b*1024+h*32+w; o=ph*48+pw*3+c
#pragma unroll
  for (int j = 0; j < 3; ++j) {
    const int o  = n0 + wid * 48 + (j << 4) + lr;
    const float bv = bias[o];
    const int c  = o % 3;
    const int oq = o / 3;
    const int pw = oq & 15;
    const int ph = oq >> 4;
#pragma unroll
    for (int i = 0; i < 4; ++i) {
#pragma unroll
      for (int r = 0; r < 4; ++r) {
        const int m   = m0 + (i << 4) + (lq << 2) + r;
        const int bb  = m >> 10;
        const int ntk = m & 1023;
        const int hh  = ntk >> 5;
        const int ww  = ntk & 31;
        const size_t idx = (((size_t)(bb * 3 + c) << 9) + (hh << 4) + ph) * 512 + (ww << 4) + pw;
        out[idx] = acc[i][j][r] + bv;
      }
    }
  }
}

extern "C" void kernel_launch(void* const* d_in, const int* in_sizes, int n_in,
                              void* d_out, int out_size, void* d_ws, size_t ws_size,
                              hipStream_t stream) {
  const float* x    = (const float*)d_in[0];
  const float* lnw  = (const float*)d_in[1];
  const float* lnb  = (const float*)d_in[2];
  const float* W    = (const float*)d_in[3];
  const float* bias = (const float*)d_in[4];
  float* out = (float*)d_out;

  const size_t wbBytes = (size_t)ODIM * DDIM * sizeof(__hip_bfloat16);
  const bool useWb = ws_size >= wbBytes;
  __hip_bfloat16* Wb = (__hip_bfloat16*)d_ws;

  const size_t lds = (size_t)(2 * BM * BK + 2 * BN * BK) * sizeof(__hip_bfloat16)
                   + 2 * BM * sizeof(float);  // 57856 B

  const dim3 grid((M_TOT / BM) * (ODIM / BN));  // 1024
  const dim3 blk(NTHR);

  if (useWb) {
    wconv_kernel<<<dim3(768), dim3(256), 0, stream>>>((const float4*)W, (ushort4*)Wb,
                                                      ODIM * DDIM / 4);
    fused_kernel<true><<<grid, blk, lds, stream>>>(x, lnw, lnb, W, Wb, bias, out);
  } else {
    fused_kernel<false><<<grid, blk, lds, stream>>>(x, lnw, lnb, W, nullptr, bias, out);
  }
}

// Round 2
// 296.584 us; speedup vs baseline: 1.0055x; 1.0055x over previous
//
#include <hip/hip_runtime.h>
#include <hip/hip_bf16.h>

#define M_TOT 32768
#define DDIM  1024
#define ODIM  768
#define LN_EPS 1e-5f

#define BM 64
#define BK 32
#define NTHR 1024

typedef __attribute__((__ext_vector_type__(8))) short bf16x8;
typedef __attribute__((__ext_vector_type__(4))) float f32x4;

__device__ __forceinline__ unsigned short f2bf(float f) {
  union { __hip_bfloat16 h; unsigned short u; } cv;
  cv.h = __float2bfloat16(f);
  return cv.u;
}

__device__ __forceinline__ float silu_f(float v) {
  return v / (1.f + __expf(-v));
}

__global__ void wconv_kernel(const float4* __restrict__ Wf, ushort4* __restrict__ Wb, int n4) {
  int i = blockIdx.x * blockDim.x + threadIdx.x;
  if (i >= n4) return;
  float4 v = Wf[i];
  ushort4 o;
  o.x = f2bf(v.x); o.y = f2bf(v.y); o.z = f2bf(v.z); o.w = f2bf(v.w);
  Wb[i] = o;
}

// LDS map: As [64 rows][64 B] = 4096 B | Bs [768 rows][64 B] = 49152 B at +4096
// stats (2*64 floats) at +53248. Epilogue reuses bytes [0, 49152) as the
// output-order chunk buffer (16 tokens x 768 f32).
#define AS_OFF 0
#define BS_OFF 4096
#define ST_OFF 53248
#define LDS_BYTES 53760

template <bool USE_WB>
__global__ __launch_bounds__(NTHR, 4)
void fused_kernel(const float* __restrict__ x,
                  const float* __restrict__ lnw,
                  const float* __restrict__ lnb,
                  const float* __restrict__ Wf,
                  const __hip_bfloat16* __restrict__ Wb,
                  const float* __restrict__ bias,
                  float* __restrict__ out)
{
  extern __shared__ char smem[];
  char* AsBase = smem + AS_OFF;
  char* BsBase = smem + BS_OFF;
  float* smean = (float*)(smem + ST_OFF);
  float* srstd = smean + BM;

  const int tid = threadIdx.x;
  const int m0  = blockIdx.x * BM;          // 512 blocks, full-N tiles
  const int bb   = m0 >> 10;                // batch
  const int h0   = (m0 & 1023) >> 5;        // first h row (block = 2 h rows)

  // ---------- pass 0: LayerNorm stats, 16 threads per row ----------
  {
    const int row = tid >> 4;
    const int sub = tid & 15;
    const float4* xr = (const float4*)(x + (size_t)(m0 + row) * DDIM);
    float s = 0.f, ss = 0.f;
#pragma unroll 4
    for (int j = 0; j < 16; ++j) {
      float4 v = xr[sub + (j << 4)];
      s  += v.x + v.y + v.z + v.w;
      ss += v.x * v.x + v.y * v.y + v.z * v.z + v.w * v.w;
    }
#pragma unroll
    for (int off = 1; off < 16; off <<= 1) {
      s  += __shfl_xor(s, off);
      ss += __shfl_xor(ss, off);
    }
    if (sub == 0) {
      float mean = s * (1.f / 1024.f);
      float var  = ss * (1.f / 1024.f) - mean * mean;
      smean[row] = mean;
      srstd[row] = rsqrtf(var + LN_EPS);
    }
  }
  __syncthreads();

  // ---------- staging indices ----------
  // A: thread -> (row = tid>>4, 2 consecutive elems at col = (tid&15)*2)
  const int arow  = tid >> 4;
  const int acol2 = tid & 15;
  const int aOff  = (m0 + arow) * DDIM + (acol2 << 1);
  const int aDst  = (arow << 6) + ((((acol2 >> 2) ^ ((arow >> 2) & 3)) << 4)) + ((acol2 & 3) << 2);
  const float aMean = smean[arow];
  const float aRstd = srstd[arow];

  int bOff[3], bDst[3];
  int bOffF[6], bDstF[6];
  if constexpr (USE_WB) {
#pragma unroll
    for (int c = 0; c < 3; ++c) {
      int idx = tid + (c << 10);            // 0..3071 over 768 rows x 4 slots
      int r = idx >> 2, kb = idx & 3;
      bOff[c] = r * DDIM + (kb << 3);
      bDst[c] = (r << 6) + ((kb ^ ((r >> 2) & 3)) << 4);
    }
  } else {
#pragma unroll
    for (int c = 0; c < 6; ++c) {
      int idx = tid + (c << 10);            // 0..6143 over 768 rows x 8 f4
      int r = idx >> 3, c4 = idx & 7;
      bOffF[c] = r * DDIM + (c4 << 2);
      bDstF[c] = (r << 6) + ((((c4 >> 1) ^ ((r >> 2) & 3)) << 4)) + ((c4 & 1) << 3);
    }
  }

  // ---------- MFMA fragment read offsets ----------
  const int lane = tid & 63;
  const int wid  = tid >> 6;                // 16 waves: 1M x 16N, 48 cols each
  const int lr   = lane & 15;
  const int lq   = lane >> 4;
  const int kswz = (lq ^ ((lr >> 2) & 3)) << 4;
  int aRd[4], bRd[3];
#pragma unroll
  for (int i = 0; i < 4; ++i) aRd[i] = (((i << 4) + lr) << 6) + kswz;
#pragma unroll
  for (int j = 0; j < 3; ++j) bRd[j] = ((wid * 48 + (j << 4) + lr) << 6) + kswz;

  float2 aReg, lwReg, lbReg;
  int4 bReg[3];
  float4 bRegF[6];

  auto loadTile = [&](int tt) {
    const int k0 = tt * BK;
    aReg  = *(const float2*)(x + aOff + k0);
    lwReg = *(const float2*)(lnw + (acol2 << 1) + k0);
    lbReg = *(const float2*)(lnb + (acol2 << 1) + k0);
    if constexpr (USE_WB) {
#pragma unroll
      for (int c = 0; c < 3; ++c)
        bReg[c] = *(const int4*)((const unsigned short*)Wb + bOff[c] + k0);
    } else {
#pragma unroll
      for (int c = 0; c < 6; ++c)
        bRegF[c] = *(const float4*)(Wf + bOffF[c] + k0);
    }
  };

  auto storeTile = [&]() {
    float hx = (aReg.x - aMean) * aRstd * lwReg.x + lbReg.x;
    float hy = (aReg.y - aMean) * aRstd * lwReg.y + lbReg.y;
    hx = silu_f(hx); hy = silu_f(hy);
    ushort2 ap; ap.x = f2bf(hx); ap.y = f2bf(hy);
    *(ushort2*)(AsBase + aDst) = ap;
    if constexpr (USE_WB) {
#pragma unroll
      for (int c = 0; c < 3; ++c)
        *(int4*)(BsBase + bDst[c]) = bReg[c];
    } else {
#pragma unroll
      for (int c = 0; c < 6; ++c) {
        float4 w = bRegF[c];
        ushort4 bp; bp.x = f2bf(w.x); bp.y = f2bf(w.y); bp.z = f2bf(w.z); bp.w = f2bf(w.w);
        *(ushort4*)(BsBase + bDstF[c]) = bp;
      }
    }
  };

  f32x4 acc[4][3];
#pragma unroll
  for (int i = 0; i < 4; ++i)
#pragma unroll
    for (int j = 0; j < 3; ++j)
      acc[i][j] = (f32x4){0.f, 0.f, 0.f, 0.f};

  loadTile(0);
  storeTile();
  __syncthreads();

  for (int t = 0; t < 32; ++t) {
    if (t < 31) loadTile(t + 1);            // issue next-tile global loads early
    bf16x8 af[4], bfr[3];
#pragma unroll
    for (int i = 0; i < 4; ++i) af[i] = *(const bf16x8*)(AsBase + aRd[i]);
#pragma unroll
    for (int j = 0; j < 3; ++j) bfr[j] = *(const bf16x8*)(BsBase + bRd[j]);
#pragma unroll
    for (int i = 0; i < 4; ++i)
#pragma unroll
      for (int j = 0; j < 3; ++j)
        acc[i][j] = __builtin_amdgcn_mfma_f32_16x16x32_bf16(af[i], bfr[j], acc[i][j], 0, 0, 0);
    __syncthreads();                        // all waves done reading buffer
    if (t < 31) storeTile();                // LN+SiLU+cast + ds_write next tile
    __syncthreads();                        // writes visible
  }

  // ---------- epilogue: LDS repack to output order, coalesced f4 stores ----
  // chunk i = 16 tokens (one i-frag row-block); chunk LDS = 48 runs x 1 KB,
  // run = (c,ph), within run: w_local*16 + pw (dwords).
  float* ldsF = (float*)smem;

  float bv[3]; int cv[3], phv[3], pwv[3];
#pragma unroll
  for (int j = 0; j < 3; ++j) {
    const int o = wid * 48 + (j << 4) + lr;
    bv[j]  = bias[o];
    cv[j]  = o % 3;
    const int oq = o / 3;
    pwv[j] = oq & 15;
    phv[j] = oq >> 4;
  }

#pragma unroll
  for (int i = 0; i < 4; ++i) {
    // write phase: this wave's acc[i][*] into output-order chunk
#pragma unroll
    for (int j = 0; j < 3; ++j) {
#pragma unroll
      for (int r = 0; r < 4; ++r) {
        const int wl  = (lq << 2) + r;
        const int lin = ((cv[j] * 16 + phv[j]) << 8) + (wl << 4) + pwv[j];
        const int dws = lin ^ (cv[j] << 2) ^ (((lin >> 6) & 1) << 4);
        ldsF[dws] = acc[i][j][r] + bv[j];
      }
    }
    __syncthreads();
    // read phase: 3072 float4s in output order -> contiguous 1 KB runs
    const int hq = h0 + (i >> 1);
    const int w0 = (i & 1) << 4;
#pragma unroll
    for (int q = 0; q < 3; ++q) {
      const int g4  = (q << 10) + tid;
      const int dw  = g4 << 2;
      const int run = dw >> 8;
      const int c   = run >> 4;
      const int ph  = run & 15;
      const int wl  = (dw >> 4) & 15;
      const int pw  = dw & 15;              // 4-aligned
      const int dws = dw ^ (c << 2) ^ (((dw >> 6) & 1) << 4);
      float4 v = *(const float4*)(ldsF + dws);
      const size_t idx = (((size_t)(bb * 3 + c)) << 18)
                       + ((size_t)((hq << 4) + ph) << 9)
                       + ((w0 + wl) << 4) + pw;
      *(float4*)(out + idx) = v;
    }
    __syncthreads();                        // before next chunk's writes
  }
}

extern "C" void kernel_launch(void* const* d_in, const int* in_sizes, int n_in,
                              void* d_out, int out_size, void* d_ws, size_t ws_size,
                              hipStream_t stream) {
  const float* x    = (const float*)d_in[0];
  const float* lnw  = (const float*)d_in[1];
  const float* lnb  = (const float*)d_in[2];
  const float* W    = (const float*)d_in[3];
  const float* bias = (const float*)d_in[4];
  float* out = (float*)d_out;

  const size_t wbBytes = (size_t)ODIM * DDIM * sizeof(__hip_bfloat16);
  const bool useWb = ws_size >= wbBytes;
  __hip_bfloat16* Wb = (__hip_bfloat16*)d_ws;

  const dim3 grid(M_TOT / BM);              // 512 blocks, full-N
  const dim3 blk(NTHR);

  if (useWb) {
    wconv_kernel<<<dim3(768), dim3(256), 0, stream>>>((const float4*)W, (ushort4*)Wb,
                                                      ODIM * DDIM / 4);
    fused_kernel<true><<<grid, blk, LDS_BYTES, stream>>>(x, lnw, lnb, W, Wb, bias, out);
  } else {
    fused_kernel<false><<<grid, blk, LDS_BYTES, stream>>>(x, lnw, lnb, W, nullptr, bias, out);
  }
}

// Round 3
// 112.727 us; speedup vs baseline: 2.6455x; 2.6310x over previous
//
#include <hip/hip_runtime.h>
#include <hip/hip_bf16.h>

#define M_TOT 32768
#define DDIM  1024
#define ODIM  768
#define LN_EPS 1e-5f

typedef __attribute__((__ext_vector_type__(8))) short bf16x8;
typedef __attribute__((__ext_vector_type__(4))) float f32x4;

__device__ __forceinline__ unsigned short f2bf(float f) {
  union { __hip_bfloat16 h; unsigned short u; } cv;
  cv.h = __float2bfloat16(f);
  return cv.u;
}

__device__ __forceinline__ float silu_f(float v) {
  return v / (1.f + __expf(-v));
}

__global__ void wconv_kernel(const float4* __restrict__ Wf, ushort4* __restrict__ Wb, int n4) {
  int i = blockIdx.x * blockDim.x + threadIdx.x;
  if (i >= n4) return;
  float4 v = Wf[i];
  ushort4 o;
  o.x = f2bf(v.x); o.y = f2bf(v.y); o.z = f2bf(v.z); o.w = f2bf(v.w);
  Wb[i] = o;
}

// ===================== kernel 1: LN + SiLU -> h (bf16) =====================
__global__ __launch_bounds__(256)
void ln_silu_kernel(const float* __restrict__ x, const float* __restrict__ lnw,
                    const float* __restrict__ lnb, __hip_bfloat16* __restrict__ h)
{
  const int tid  = threadIdx.x;
  const int lane = tid & 63;
  const int wid  = tid >> 6;
  const int row  = blockIdx.x * 4 + wid;

  const float4* xr = (const float4*)(x + (size_t)row * DDIM);
  float4 v[4];
#pragma unroll
  for (int jj = 0; jj < 4; ++jj) v[jj] = xr[lane + 64 * jj];

  float s = 0.f, ss = 0.f;
#pragma unroll
  for (int jj = 0; jj < 4; ++jj) {
    float4 a = v[jj];
    s  += a.x + a.y + a.z + a.w;
    ss += a.x * a.x + a.y * a.y + a.z * a.z + a.w * a.w;
  }
#pragma unroll
  for (int off = 1; off < 64; off <<= 1) {
    s  += __shfl_xor(s, off);
    ss += __shfl_xor(ss, off);
  }
  const float mean = s * (1.f / 1024.f);
  const float rstd = rsqrtf(ss * (1.f / 1024.f) - mean * mean + LN_EPS);

  ushort4* hr = (ushort4*)(h + (size_t)row * DDIM);
#pragma unroll
  for (int jj = 0; jj < 4; ++jj) {
    float4 wv = ((const float4*)lnw)[lane + 64 * jj];
    float4 bv = ((const float4*)lnb)[lane + 64 * jj];
    float4 a  = v[jj];
    float e0 = silu_f((a.x - mean) * rstd * wv.x + bv.x);
    float e1 = silu_f((a.y - mean) * rstd * wv.y + bv.y);
    float e2 = silu_f((a.z - mean) * rstd * wv.z + bv.z);
    float e3 = silu_f((a.w - mean) * rstd * wv.w + bv.w);
    ushort4 o; o.x = f2bf(e0); o.y = f2bf(e1); o.z = f2bf(e2); o.w = f2bf(e3);
    hr[lane + 64 * jj] = o;
  }
}

// ===================== kernel 2: GEMM + rearrange =====================
// 128x192 tile, BK=32, 256 thr (4 waves as 2Mx2N, each 64x96), 2-phase dbuf
// via global_load_lds with pre-swizzled source (chunk ^= row&3 on 16B slots).
#define GBM 128
#define GBN 192
#define ABYTES 8192    // 128 rows x 64 B
#define BBYTES 12288   // 192 rows x 64 B
#define BUFB   20480
#define GLDS   40960

__device__ __forceinline__ void gload16(const void* g, void* l) {
  __builtin_amdgcn_global_load_lds(
      (const __attribute__((address_space(1))) unsigned int*)g,
      (__attribute__((address_space(3))) unsigned int*)l, 16, 0, 0);
}

__global__ __launch_bounds__(256, 3)
void gemm_kernel(const __hip_bfloat16* __restrict__ h,
                 const __hip_bfloat16* __restrict__ Wb,
                 const float* __restrict__ bias,
                 float* __restrict__ out)
{
  extern __shared__ char smem[];
  const int tid  = threadIdx.x;
  const int lane = tid & 63;
  const int w    = tid >> 6;

  // bijective XCD swizzle (1024 % 8 == 0); nt fastest so same-XCD blocks share A
  const int wg = blockIdx.x;
  const int sv = ((wg & 7) << 7) + (wg >> 3);
  const int mt = sv >> 2, nt = sv & 3;
  const int m0 = mt * GBM, n0 = nt * GBN;

  // staging slot precompute: slot -> (row, swizzled source chunk)
  int aRowQ[2], aChkQ[2], bRowQ[3], bChkQ[3];
#pragma unroll
  for (int q = 0; q < 2; ++q) {
    int sA = ((w * 2 + q) << 6) + lane;
    int row = sA >> 2, chk = sA & 3;
    aRowQ[q] = row;
    aChkQ[q] = (chk ^ (row & 3)) << 3;   // element offset of 16B chunk
  }
#pragma unroll
  for (int q = 0; q < 3; ++q) {
    int sB = ((w * 3 + q) << 6) + lane;
    int row = sB >> 2, chk = sB & 3;
    bRowQ[q] = row;
    bChkQ[q] = (chk ^ (row & 3)) << 3;
  }

  // MFMA fragment LDS read offsets (swizzle-matched, conflict-free)
  const int wm = w >> 1, wn = w & 1;
  const int lr = lane & 15, lq = lane >> 4;
  int aRd[4], bRd[6];
#pragma unroll
  for (int i = 0; i < 4; ++i) {
    int row = wm * 64 + i * 16 + lr;
    aRd[i] = row * 64 + ((lq ^ (row & 3)) << 4);
  }
#pragma unroll
  for (int j = 0; j < 6; ++j) {
    int row = wn * 96 + j * 16 + lr;
    bRd[j] = ABYTES + row * 64 + ((lq ^ (row & 3)) << 4);
  }

  auto stage = [&](int buf, int t) {
    const int k0 = t << 5;
    char* base = smem + buf * BUFB;
#pragma unroll
    for (int q = 0; q < 2; ++q)
      gload16(h + (size_t)(m0 + aRowQ[q]) * DDIM + k0 + aChkQ[q],
              base + ((w * 2 + q) << 10));
#pragma unroll
    for (int q = 0; q < 3; ++q)
      gload16(Wb + (size_t)(n0 + bRowQ[q]) * DDIM + k0 + bChkQ[q],
              base + ABYTES + ((w * 3 + q) << 10));
  };

  f32x4 acc[4][6];
#pragma unroll
  for (int i = 0; i < 4; ++i)
#pragma unroll
    for (int j = 0; j < 6; ++j)
      acc[i][j] = (f32x4){0.f, 0.f, 0.f, 0.f};

  stage(0, 0);
  __syncthreads();
  int cur = 0;
  for (int t = 0; t < 32; ++t) {
    if (t < 31) stage(cur ^ 1, t + 1);      // async loads into other buffer
    const char* bb = smem + cur * BUFB;
    bf16x8 af[4], bfq[6];
#pragma unroll
    for (int i = 0; i < 4; ++i) af[i] = *(const bf16x8*)(bb + aRd[i]);
#pragma unroll
    for (int j = 0; j < 6; ++j) bfq[j] = *(const bf16x8*)(bb + bRd[j]);
#pragma unroll
    for (int i = 0; i < 4; ++i)
#pragma unroll
      for (int j = 0; j < 6; ++j)
        acc[i][j] = __builtin_amdgcn_mfma_f32_16x16x32_bf16(af[i], bfq[j], acc[i][j], 0, 0, 0);
    __syncthreads();                        // drains vmcnt; cur free, cur^1 ready
    cur ^= 1;
  }

  // ---------- epilogue: repack 16-token chunks to output order ----------
  const int b   = m0 >> 10;
  const int hl0 = (m0 & 1023) >> 5;
  float bv[6]; int cj[6], pwj[6], phj[6];
#pragma unroll
  for (int j = 0; j < 6; ++j) {
    int o = wn * 96 + j * 16 + lr;
    bv[j]  = bias[n0 + o];
    cj[j]  = o % 3;
    int oq = o / 3;
    pwj[j] = oq & 15;
    phj[j] = oq >> 4;
  }
  float*  ldsF = (float*)smem;
  float4* ldsV = (float4*)smem;
#pragma unroll
  for (int g = 0; g < 8; ++g) {
    if (wm == (g >> 2)) {
      const int i_f = g & 3;
#pragma unroll
      for (int j = 0; j < 6; ++j)
#pragma unroll
        for (int r = 0; r < 4; ++r)
          ldsF[((cj[j] * 4 + phj[j]) << 8) + ((lq * 4 + r) << 4) + pwj[j]] =
              acc[i_f][j][r] + bv[j];
    }
    __syncthreads();
    const int orow_base = ((hl0 + (g >> 1)) << 4) + (nt << 2);
    const int wbase = (g & 1) << 4;
#pragma unroll
    for (int q = 0; q < 3; ++q) {
      int f4  = (q << 8) + tid;
      int run = f4 >> 6;
      int tk  = (f4 >> 2) & 15;
      int pw0 = (f4 & 3) << 2;
      int c   = run >> 2;
      int ph  = run & 3;
      float4 v = ldsV[f4];
      size_t idx = (((size_t)(b * 3 + c)) << 18)
                 + (size_t)(orow_base + ph) * 512
                 + ((wbase + tk) << 4) + pw0;
      *(float4*)(out + idx) = v;
    }
    __syncthreads();
  }
}

// ===================== fallback: round-2 fused kernel =====================
#define BM 64
#define BK 32
#define NTHR 1024
#define AS_OFF 0
#define BS_OFF 4096
#define ST_OFF 53248
#define LDS_BYTES 53760

template <bool USE_WB>
__global__ __launch_bounds__(NTHR, 4)
void fused_kernel(const float* __restrict__ x,
                  const float* __restrict__ lnw,
                  const float* __restrict__ lnb,
                  const float* __restrict__ Wf,
                  const __hip_bfloat16* __restrict__ Wb,
                  const float* __restrict__ bias,
                  float* __restrict__ out)
{
  extern __shared__ char smem[];
  char* AsBase = smem + AS_OFF;
  char* BsBase = smem + BS_OFF;
  float* smean = (float*)(smem + ST_OFF);
  float* srstd = smean + BM;

  const int tid = threadIdx.x;
  const int m0  = blockIdx.x * BM;
  const int bb   = m0 >> 10;
  const int h0   = (m0 & 1023) >> 5;

  {
    const int row = tid >> 4;
    const int sub = tid & 15;
    const float4* xr = (const float4*)(x + (size_t)(m0 + row) * DDIM);
    float s = 0.f, ss = 0.f;
#pragma unroll 4
    for (int j = 0; j < 16; ++j) {
      float4 v = xr[sub + (j << 4)];
      s  += v.x + v.y + v.z + v.w;
      ss += v.x * v.x + v.y * v.y + v.z * v.z + v.w * v.w;
    }
#pragma unroll
    for (int off = 1; off < 16; off <<= 1) {
      s  += __shfl_xor(s, off);
      ss += __shfl_xor(ss, off);
    }
    if (sub == 0) {
      float mean = s * (1.f / 1024.f);
      float var  = ss * (1.f / 1024.f) - mean * mean;
      smean[row] = mean;
      srstd[row] = rsqrtf(var + LN_EPS);
    }
  }
  __syncthreads();

  const int arow  = tid >> 4;
  const int acol2 = tid & 15;
  const int aOff  = (m0 + arow) * DDIM + (acol2 << 1);
  const int aDst  = (arow << 6) + ((((acol2 >> 2) ^ ((arow >> 2) & 3)) << 4)) + ((acol2 & 3) << 2);
  const float aMean = smean[arow];
  const float aRstd = srstd[arow];

  int bOff[3], bDst[3];
  int bOffF[6], bDstF[6];
  if constexpr (USE_WB) {
#pragma unroll
    for (int c = 0; c < 3; ++c) {
      int idx = tid + (c << 10);
      int r = idx >> 2, kb = idx & 3;
      bOff[c] = r * DDIM + (kb << 3);
      bDst[c] = (r << 6) + ((kb ^ ((r >> 2) & 3)) << 4);
    }
  } else {
#pragma unroll
    for (int c = 0; c < 6; ++c) {
      int idx = tid + (c << 10);
      int r = idx >> 3, c4 = idx & 7;
      bOffF[c] = r * DDIM + (c4 << 2);
      bDstF[c] = (r << 6) + ((((c4 >> 1) ^ ((r >> 2) & 3)) << 4)) + ((c4 & 1) << 3);
    }
  }

  const int lane = tid & 63;
  const int wid  = tid >> 6;
  const int lr   = lane & 15;
  const int lq   = lane >> 4;
  const int kswz = (lq ^ ((lr >> 2) & 3)) << 4;
  int aRd[4], bRd[3];
#pragma unroll
  for (int i = 0; i < 4; ++i) aRd[i] = (((i << 4) + lr) << 6) + kswz;
#pragma unroll
  for (int j = 0; j < 3; ++j) bRd[j] = ((wid * 48 + (j << 4) + lr) << 6) + kswz;

  float2 aReg, lwReg, lbReg;
  int4 bReg[3];
  float4 bRegF[6];

  auto loadTile = [&](int tt) {
    const int k0 = tt * BK;
    aReg  = *(const float2*)(x + aOff + k0);
    lwReg = *(const float2*)(lnw + (acol2 << 1) + k0);
    lbReg = *(const float2*)(lnb + (acol2 << 1) + k0);
    if constexpr (USE_WB) {
#pragma unroll
      for (int c = 0; c < 3; ++c)
        bReg[c] = *(const int4*)((const unsigned short*)Wb + bOff[c] + k0);
    } else {
#pragma unroll
      for (int c = 0; c < 6; ++c)
        bRegF[c] = *(const float4*)(Wf + bOffF[c] + k0);
    }
  };

  auto storeTile = [&]() {
    float hx = (aReg.x - aMean) * aRstd * lwReg.x + lbReg.x;
    float hy = (aReg.y - aMean) * aRstd * lwReg.y + lbReg.y;
    hx = silu_f(hx); hy = silu_f(hy);
    ushort2 ap; ap.x = f2bf(hx); ap.y = f2bf(hy);
    *(ushort2*)(AsBase + aDst) = ap;
    if constexpr (USE_WB) {
#pragma unroll
      for (int c = 0; c < 3; ++c)
        *(int4*)(BsBase + bDst[c]) = bReg[c];
    } else {
#pragma unroll
      for (int c = 0; c < 6; ++c) {
        float4 wv = bRegF[c];
        ushort4 bp; bp.x = f2bf(wv.x); bp.y = f2bf(wv.y); bp.z = f2bf(wv.z); bp.w = f2bf(wv.w);
        *(ushort4*)(BsBase + bDstF[c]) = bp;
      }
    }
  };

  f32x4 acc[4][3];
#pragma unroll
  for (int i = 0; i < 4; ++i)
#pragma unroll
    for (int j = 0; j < 3; ++j)
      acc[i][j] = (f32x4){0.f, 0.f, 0.f, 0.f};

  loadTile(0);
  storeTile();
  __syncthreads();

  for (int t = 0; t < 32; ++t) {
    if (t < 31) loadTile(t + 1);
    bf16x8 af[4], bfr[3];
#pragma unroll
    for (int i = 0; i < 4; ++i) af[i] = *(const bf16x8*)(AsBase + aRd[i]);
#pragma unroll
    for (int j = 0; j < 3; ++j) bfr[j] = *(const bf16x8*)(BsBase + bRd[j]);
#pragma unroll
    for (int i = 0; i < 4; ++i)
#pragma unroll
      for (int j = 0; j < 3; ++j)
        acc[i][j] = __builtin_amdgcn_mfma_f32_16x16x32_bf16(af[i], bfr[j], acc[i][j], 0, 0, 0);
    __syncthreads();
    if (t < 31) storeTile();
    __syncthreads();
  }

  float* ldsF = (float*)smem;
  float bv[3]; int cv[3], phv[3], pwv[3];
#pragma unroll
  for (int j = 0; j < 3; ++j) {
    const int o = wid * 48 + (j << 4) + lr;
    bv[j]  = bias[o];
    cv[j]  = o % 3;
    const int oq = o / 3;
    pwv[j] = oq & 15;
    phv[j] = oq >> 4;
  }

#pragma unroll
  for (int i = 0; i < 4; ++i) {
#pragma unroll
    for (int j = 0; j < 3; ++j) {
#pragma unroll
      for (int r = 0; r < 4; ++r) {
        const int wl  = (lq << 2) + r;
        const int lin = ((cv[j] * 16 + phv[j]) << 8) + (wl << 4) + pwv[j];
        const int dws = lin ^ (cv[j] << 2) ^ (((lin >> 6) & 1) << 4);
        ldsF[dws] = acc[i][j][r] + bv[j];
      }
    }
    __syncthreads();
    const int hq = h0 + (i >> 1);
    const int w0 = (i & 1) << 4;
#pragma unroll
    for (int q = 0; q < 3; ++q) {
      const int g4  = (q << 10) + tid;
      const int dw  = g4 << 2;
      const int run = dw >> 8;
      const int c   = run >> 4;
      const int ph  = run & 15;
      const int wl  = (dw >> 4) & 15;
      const int pw  = dw & 15;
      const int dws = dw ^ (c << 2) ^ (((dw >> 6) & 1) << 4);
      float4 v = *(const float4*)(ldsF + dws);
      const size_t idx = (((size_t)(bb * 3 + c)) << 18)
                       + ((size_t)((hq << 4) + ph) << 9)
                       + ((w0 + wl) << 4) + pw;
      *(float4*)(out + idx) = v;
    }
    __syncthreads();
  }
}

extern "C" void kernel_launch(void* const* d_in, const int* in_sizes, int n_in,
                              void* d_out, int out_size, void* d_ws, size_t ws_size,
                              hipStream_t stream) {
  const float* x    = (const float*)d_in[0];
  const float* lnw  = (const float*)d_in[1];
  const float* lnb  = (const float*)d_in[2];
  const float* W    = (const float*)d_in[3];
  const float* bias = (const float*)d_in[4];
  float* out = (float*)d_out;

  const size_t wbBytes = (size_t)ODIM * DDIM * sizeof(__hip_bfloat16);   // 1.5 MB
  const size_t hBytes  = (size_t)M_TOT * DDIM * sizeof(__hip_bfloat16);  // 64 MB
  __hip_bfloat16* Wb = (__hip_bfloat16*)d_ws;
  __hip_bfloat16* hb = (__hip_bfloat16*)((char*)d_ws + wbBytes);

  if (ws_size >= wbBytes + hBytes) {
    wconv_kernel<<<dim3(768), dim3(256), 0, stream>>>((const float4*)W, (ushort4*)Wb,
                                                      ODIM * DDIM / 4);
    ln_silu_kernel<<<dim3(M_TOT / 4), dim3(256), 0, stream>>>(x, lnw, lnb, hb);
    gemm_kernel<<<dim3((M_TOT / GBM) * (ODIM / GBN)), dim3(256), GLDS, stream>>>(hb, Wb, bias, out);
  } else if (ws_size >= wbBytes) {
    wconv_kernel<<<dim3(768), dim3(256), 0, stream>>>((const float4*)W, (ushort4*)Wb,
                                                      ODIM * DDIM / 4);
    fused_kernel<true><<<dim3(M_TOT / BM), dim3(NTHR), LDS_BYTES, stream>>>(
        x, lnw, lnb, W, Wb, bias, out);
  } else {
    fused_kernel<false><<<dim3(M_TOT / BM), dim3(NTHR), LDS_BYTES, stream>>>(
        x, lnw, lnb, W, nullptr, bias, out);
  }
}

// Round 4
// 109.671 us; speedup vs baseline: 2.7192x; 1.0279x over previous
//
#include <hip/hip_runtime.h>
#include <hip/hip_bf16.h>

#define M_TOT 32768
#define DDIM  1024
#define ODIM  768
#define LN_EPS 1e-5f

typedef __attribute__((__ext_vector_type__(8))) short bf16x8;
typedef __attribute__((__ext_vector_type__(4))) float f32x4;

__device__ __forceinline__ unsigned short f2bf(float f) {
  union { __hip_bfloat16 h; unsigned short u; } cv;
  cv.h = __float2bfloat16(f);
  return cv.u;
}

__device__ __forceinline__ float silu_f(float v) {
  return v / (1.f + __expf(-v));
}

__global__ void wconv_kernel(const float4* __restrict__ Wf, ushort4* __restrict__ Wb, int n4) {
  int i = blockIdx.x * blockDim.x + threadIdx.x;
  if (i >= n4) return;
  float4 v = Wf[i];
  ushort4 o;
  o.x = f2bf(v.x); o.y = f2bf(v.y); o.z = f2bf(v.z); o.w = f2bf(v.w);
  Wb[i] = o;
}

// ===================== kernel 1: LN + SiLU -> h (bf16) =====================
__global__ __launch_bounds__(256)
void ln_silu_kernel(const float* __restrict__ x, const float* __restrict__ lnw,
                    const float* __restrict__ lnb, __hip_bfloat16* __restrict__ h)
{
  const int tid  = threadIdx.x;
  const int lane = tid & 63;
  const int wid  = tid >> 6;
  const int row  = blockIdx.x * 4 + wid;

  const float4* xr = (const float4*)(x + (size_t)row * DDIM);
  float4 v[4];
#pragma unroll
  for (int jj = 0; jj < 4; ++jj) v[jj] = xr[lane + 64 * jj];

  float s = 0.f, ss = 0.f;
#pragma unroll
  for (int jj = 0; jj < 4; ++jj) {
    float4 a = v[jj];
    s  += a.x + a.y + a.z + a.w;
    ss += a.x * a.x + a.y * a.y + a.z * a.z + a.w * a.w;
  }
#pragma unroll
  for (int off = 1; off < 64; off <<= 1) {
    s  += __shfl_xor(s, off);
    ss += __shfl_xor(ss, off);
  }
  const float mean = s * (1.f / 1024.f);
  const float rstd = rsqrtf(ss * (1.f / 1024.f) - mean * mean + LN_EPS);

  ushort4* hr = (ushort4*)(h + (size_t)row * DDIM);
#pragma unroll
  for (int jj = 0; jj < 4; ++jj) {
    float4 wv = ((const float4*)lnw)[lane + 64 * jj];
    float4 bv = ((const float4*)lnb)[lane + 64 * jj];
    float4 a  = v[jj];
    float e0 = silu_f((a.x - mean) * rstd * wv.x + bv.x);
    float e1 = silu_f((a.y - mean) * rstd * wv.y + bv.y);
    float e2 = silu_f((a.z - mean) * rstd * wv.z + bv.z);
    float e3 = silu_f((a.w - mean) * rstd * wv.w + bv.w);
    ushort4 o; o.x = f2bf(e0); o.y = f2bf(e1); o.z = f2bf(e2); o.w = f2bf(e3);
    hr[lane + 64 * jj] = o;
  }
}

// ========== kernel 2: GEMM + rearrange, ring-3 counted-vmcnt pipeline ======
// BM=128, BN=192, BK=32; 512 thr = 8 waves (2M x 4N), wave C = 64x48.
// LDS: 3 bufs x (A 8192 + B 12288) = 61440 B. Prefetch depth 2; steady
// vmcnt(6)/(4) per wave role; raw s_barrier; lgkmcnt(0) before release.
#define GBM 128
#define GBN 192
#define ABYTES 8192
#define BUFB   20480
#define GLDS   61440

__device__ __forceinline__ void gload16(const void* g, void* l) {
  __builtin_amdgcn_global_load_lds(
      (const __attribute__((address_space(1))) unsigned int*)g,
      (__attribute__((address_space(3))) unsigned int*)l, 16, 0, 0);
}

#define VMW(n) asm volatile("s_waitcnt vmcnt(" #n ")" ::: "memory")

__global__ __launch_bounds__(512, 4)
void gemm_kernel(const __hip_bfloat16* __restrict__ h,
                 const __hip_bfloat16* __restrict__ Wb,
                 const float* __restrict__ bias,
                 float* __restrict__ out)
{
  extern __shared__ char smem[];
  const int tid  = threadIdx.x;
  const int lane = tid & 63;
  const int w    = tid >> 6;

  // bijective XCD swizzle (1024 % 8 == 0); n fastest -> same-XCD shares A
  const int wg = blockIdx.x;
  const int sv = ((wg & 7) << 7) + (wg >> 3);
  const int mt = sv >> 2, nt = sv & 3;
  const int m0 = mt * GBM, n0 = nt * GBN;

  // ---- staging source pointers (pre-swizzled: chunk ^= row&3) ----
  const int aRow = tid >> 2;
  const int aSrc = ((tid & 3) ^ (aRow & 3)) << 3;
  const __hip_bfloat16* aPtr = h + (size_t)(m0 + aRow) * DDIM + aSrc;

  const int bRow0 = tid >> 2;
  const int bSrc0 = ((tid & 3) ^ (bRow0 & 3)) << 3;
  const __hip_bfloat16* bPtr0 = Wb + (size_t)(n0 + bRow0) * DDIM + bSrc0;
  const int s1    = 512 + tid;                // only tid<256 (waves 0-3)
  const int bRow1 = s1 >> 2;
  const int bSrc1 = ((s1 & 3) ^ (bRow1 & 3)) << 3;
  const __hip_bfloat16* bPtr1 = Wb + (size_t)(n0 + bRow1) * DDIM + bSrc1;
  const bool doB1 = (tid < 256);              // wave-uniform

  // ---- MFMA fragment LDS read offsets (swizzle-matched) ----
  const int wm = w >> 2, wn = w & 3;
  const int lr = lane & 15, lq = lane >> 4;
  int aRd[4], bRd[3];
#pragma unroll
  for (int i = 0; i < 4; ++i) {
    int row = wm * 64 + i * 16 + lr;
    aRd[i] = row * 64 + ((lq ^ (row & 3)) << 4);
  }
#pragma unroll
  for (int j = 0; j < 3; ++j) {
    int row = wn * 48 + j * 16 + lr;
    bRd[j] = ABYTES + row * 64 + ((lq ^ (row & 3)) << 4);
  }

  auto stage = [&](int t) {
    const int k0  = t << 5;
    char* base = smem + (t % 3) * BUFB;
    gload16(aPtr + k0, base + (tid << 4));
    gload16(bPtr0 + k0, base + ABYTES + (tid << 4));
    if (doB1) gload16(bPtr1 + k0, base + ABYTES + (s1 << 4));
  };

  f32x4 acc[4][3];
#pragma unroll
  for (int i = 0; i < 4; ++i)
#pragma unroll
    for (int j = 0; j < 3; ++j)
      acc[i][j] = (f32x4){0.f, 0.f, 0.f, 0.f};

  // prologue: 3 tiles in flight
  stage(0); stage(1); stage(2);

  for (int t = 0; t < 32; ++t) {
    // wait until MY stage(t) loads have landed (counted, never 0 in steady)
    if (t <= 29)      { if (w < 4) VMW(6); else VMW(4); }
    else if (t == 30) { if (w < 4) VMW(3); else VMW(2); }
    else              { VMW(0); }
    __builtin_amdgcn_s_barrier();             // all waves' stage(t) landed
    asm volatile("" ::: "memory");

    const char* bb = smem + (t % 3) * BUFB;
    bf16x8 af[4], bfq[3];
#pragma unroll
    for (int i = 0; i < 4; ++i) af[i] = *(const bf16x8*)(bb + aRd[i]);
#pragma unroll
    for (int j = 0; j < 3; ++j) bfq[j] = *(const bf16x8*)(bb + bRd[j]);

    __builtin_amdgcn_s_setprio(1);
#pragma unroll
    for (int i = 0; i < 4; ++i)
#pragma unroll
      for (int j = 0; j < 3; ++j)
        acc[i][j] = __builtin_amdgcn_mfma_f32_16x16x32_bf16(af[i], bfq[j], acc[i][j], 0, 0, 0);
    __builtin_amdgcn_s_setprio(0);

    asm volatile("s_waitcnt lgkmcnt(0)" ::: "memory");  // my reads retired
    __builtin_amdgcn_s_barrier();             // buf[t%3] free for overwrite
    asm volatile("" ::: "memory");
    if (t <= 28) stage(t + 3);                // into buf[t%3]
  }

  // ---------- epilogue: LDS repack to output order, coalesced f4 stores ----
  // chunk g = 16 tokens; buffer = [c(3)][pr(4)][tk(16)][pw(16)] f32 = 12 KB,
  // pw column XOR'd by (lq<<2) to spread write banks (reader undoes via tk>>2).
  const int b   = m0 >> 10;
  const int hq0 = (m0 & 1023) >> 5;
  float bv[3]; int cj[3], pwj[3], prj[3];
#pragma unroll
  for (int j = 0; j < 3; ++j) {
    int o = wn * 48 + j * 16 + lr;            // 0..191
    bv[j]  = bias[n0 + o];
    cj[j]  = o % 3;
    int oq = o / 3;
    pwj[j] = oq & 15;
    prj[j] = o / 48;                          // 0..3
  }
  float* ldsF = (float*)smem;

#pragma unroll
  for (int g = 0; g < 8; ++g) {
    if (wm == (g >> 2)) {
      const int i_f = g & 3;
#pragma unroll
      for (int j = 0; j < 3; ++j)
#pragma unroll
        for (int r = 0; r < 4; ++r) {
          const int tk = lq * 4 + r;
          ldsF[((cj[j] * 4 + prj[j]) << 8) + (tk << 4) + (pwj[j] ^ (lq << 2))] =
              acc[i_f][j][r] + bv[j];
        }
    }
    __syncthreads();
    const int hq = hq0 + (g >> 1);
#pragma unroll
    for (int q = 0; q < 2; ++q) {
      if (q == 1 && tid >= 256) break;        // 768 f4 total
      const int f   = (q << 9) + tid;
      const int c   = f >> 8;
      const int pr  = (f >> 6) & 3;
      const int tk  = (f >> 2) & 15;
      const int pw0 = (f & 3) << 2;
      const int lqw = tk >> 2;
      float4 v = *(const float4*)(ldsF + (((c * 4 + pr) << 8) + (tk << 4) + (pw0 ^ (lqw << 2))));
      const size_t idx = (((size_t)(b * 3 + c)) << 18)
                       + (size_t)((hq << 4) + (nt << 2) + pr) * 512
                       + ((g & 1) << 8) + (tk << 4) + pw0;
      *(float4*)(out + idx) = v;
    }
    __syncthreads();
  }
}

// ===================== fallback: fused (no workspace) =====================
#define BM 64
#define BK 32
#define NTHR 1024
#define LDS_BYTES 53760

__global__ __launch_bounds__(NTHR, 4)
void fused_kernel(const float* __restrict__ x,
                  const float* __restrict__ lnw,
                  const float* __restrict__ lnb,
                  const float* __restrict__ Wf,
                  const float* __restrict__ bias,
                  float* __restrict__ out)
{
  extern __shared__ char smem[];
  char* AsBase = smem;
  char* BsBase = smem + 4096;
  float* smean = (float*)(smem + 53248);
  float* srstd = smean + BM;

  const int tid = threadIdx.x;
  const int m0  = blockIdx.x * BM;
  const int bb   = m0 >> 10;
  const int h0   = (m0 & 1023) >> 5;

  {
    const int row = tid >> 4;
    const int sub = tid & 15;
    const float4* xr = (const float4*)(x + (size_t)(m0 + row) * DDIM);
    float s = 0.f, ss = 0.f;
#pragma unroll 4
    for (int j = 0; j < 16; ++j) {
      float4 v = xr[sub + (j << 4)];
      s  += v.x + v.y + v.z + v.w;
      ss += v.x * v.x + v.y * v.y + v.z * v.z + v.w * v.w;
    }
#pragma unroll
    for (int off = 1; off < 16; off <<= 1) {
      s  += __shfl_xor(s, off);
      ss += __shfl_xor(ss, off);
    }
    if (sub == 0) {
      float mean = s * (1.f / 1024.f);
      float var  = ss * (1.f / 1024.f) - mean * mean;
      smean[row] = mean;
      srstd[row] = rsqrtf(var + LN_EPS);
    }
  }
  __syncthreads();

  const int arow  = tid >> 4;
  const int acol2 = tid & 15;
  const int aOff  = (m0 + arow) * DDIM + (acol2 << 1);
  const int aDst  = (arow << 6) + ((((acol2 >> 2) ^ ((arow >> 2) & 3)) << 4)) + ((acol2 & 3) << 2);
  const float aMean = smean[arow];
  const float aRstd = srstd[arow];

  int bOffF[6], bDstF[6];
#pragma unroll
  for (int c = 0; c < 6; ++c) {
    int idx = tid + (c << 10);
    int r = idx >> 3, c4 = idx & 7;
    bOffF[c] = r * DDIM + (c4 << 2);
    bDstF[c] = (r << 6) + ((((c4 >> 1) ^ ((r >> 2) & 3)) << 4)) + ((c4 & 1) << 3);
  }

  const int lane = tid & 63;
  const int wid  = tid >> 6;
  const int lr   = lane & 15;
  const int lq   = lane >> 4;
  const int kswz = (lq ^ ((lr >> 2) & 3)) << 4;
  int aRd[4], bRd[3];
#pragma unroll
  for (int i = 0; i < 4; ++i) aRd[i] = (((i << 4) + lr) << 6) + kswz;
#pragma unroll
  for (int j = 0; j < 3; ++j) bRd[j] = ((wid * 48 + (j << 4) + lr) << 6) + kswz;

  float2 aReg, lwReg, lbReg;
  float4 bRegF[6];

  auto loadTile = [&](int tt) {
    const int k0 = tt * BK;
    aReg  = *(const float2*)(x + aOff + k0);
    lwReg = *(const float2*)(lnw + (acol2 << 1) + k0);
    lbReg = *(const float2*)(lnb + (acol2 << 1) + k0);
#pragma unroll
    for (int c = 0; c < 6; ++c)
      bRegF[c] = *(const float4*)(Wf + bOffF[c] + k0);
  };

  auto storeTile = [&]() {
    float hx = (aReg.x - aMean) * aRstd * lwReg.x + lbReg.x;
    float hy = (aReg.y - aMean) * aRstd * lwReg.y + lbReg.y;
    hx = silu_f(hx); hy = silu_f(hy);
    ushort2 ap; ap.x = f2bf(hx); ap.y = f2bf(hy);
    *(ushort2*)(AsBase + aDst) = ap;
#pragma unroll
    for (int c = 0; c < 6; ++c) {
      float4 wv = bRegF[c];
      ushort4 bp; bp.x = f2bf(wv.x); bp.y = f2bf(wv.y); bp.z = f2bf(wv.z); bp.w = f2bf(wv.w);
      *(ushort4*)(BsBase + bDstF[c]) = bp;
    }
  };

  f32x4 acc[4][3];
#pragma unroll
  for (int i = 0; i < 4; ++i)
#pragma unroll
    for (int j = 0; j < 3; ++j)
      acc[i][j] = (f32x4){0.f, 0.f, 0.f, 0.f};

  loadTile(0);
  storeTile();
  __syncthreads();

  for (int t = 0; t < 32; ++t) {
    if (t < 31) loadTile(t + 1);
    bf16x8 af[4], bfr[3];
#pragma unroll
    for (int i = 0; i < 4; ++i) af[i] = *(const bf16x8*)(AsBase + aRd[i]);
#pragma unroll
    for (int j = 0; j < 3; ++j) bfr[j] = *(const bf16x8*)(BsBase + bRd[j]);
#pragma unroll
    for (int i = 0; i < 4; ++i)
#pragma unroll
      for (int j = 0; j < 3; ++j)
        acc[i][j] = __builtin_amdgcn_mfma_f32_16x16x32_bf16(af[i], bfr[j], acc[i][j], 0, 0, 0);
    __syncthreads();
    if (t < 31) storeTile();
    __syncthreads();
  }

  float* ldsF = (float*)smem;
  float bv[3]; int cv[3], phv[3], pwv[3];
#pragma unroll
  for (int j = 0; j < 3; ++j) {
    const int o = wid * 48 + (j << 4) + lr;
    bv[j]  = bias[o];
    cv[j]  = o % 3;
    const int oq = o / 3;
    pwv[j] = oq & 15;
    phv[j] = oq >> 4;
  }

#pragma unroll
  for (int i = 0; i < 4; ++i) {
#pragma unroll
    for (int j = 0; j < 3; ++j) {
#pragma unroll
      for (int r = 0; r < 4; ++r) {
        const int wl  = (lq << 2) + r;
        const int lin = ((cv[j] * 16 + phv[j]) << 8) + (wl << 4) + pwv[j];
        const int dws = lin ^ (cv[j] << 2) ^ (((lin >> 6) & 1) << 4);
        ldsF[dws] = acc[i][j][r] + bv[j];
      }
    }
    __syncthreads();
    const int hq = h0 + (i >> 1);
    const int w0 = (i & 1) << 4;
#pragma unroll
    for (int q = 0; q < 3; ++q) {
      const int g4  = (q << 10) + tid;
      const int dw  = g4 << 2;
      const int run = dw >> 8;
      const int c   = run >> 4;
      const int ph  = run & 15;
      const int wl  = (dw >> 4) & 15;
      const int pw  = dw & 15;
      const int dws = dw ^ (c << 2) ^ (((dw >> 6) & 1) << 4);
      float4 v = *(const float4*)(ldsF + dws);
      const size_t idx = (((size_t)(bb * 3 + c)) << 18)
                       + ((size_t)((hq << 4) + ph) << 9)
                       + ((w0 + wl) << 4) + pw;
      *(float4*)(out + idx) = v;
    }
    __syncthreads();
  }
}

extern "C" void kernel_launch(void* const* d_in, const int* in_sizes, int n_in,
                              void* d_out, int out_size, void* d_ws, size_t ws_size,
                              hipStream_t stream) {
  const float* x    = (const float*)d_in[0];
  const float* lnw  = (const float*)d_in[1];
  const float* lnb  = (const float*)d_in[2];
  const float* W    = (const float*)d_in[3];
  const float* bias = (const float*)d_in[4];
  float* out = (float*)d_out;

  const size_t wbBytes = (size_t)ODIM * DDIM * sizeof(__hip_bfloat16);   // 1.5 MB
  const size_t hBytes  = (size_t)M_TOT * DDIM * sizeof(__hip_bfloat16);  // 64 MB
  __hip_bfloat16* Wb = (__hip_bfloat16*)d_ws;
  __hip_bfloat16* hb = (__hip_bfloat16*)((char*)d_ws + wbBytes);

  if (ws_size >= wbBytes + hBytes) {
    wconv_kernel<<<dim3(768), dim3(256), 0, stream>>>((const float4*)W, (ushort4*)Wb,
                                                      ODIM * DDIM / 4);
    ln_silu_kernel<<<dim3(M_TOT / 4), dim3(256), 0, stream>>>(x, lnw, lnb, hb);
    gemm_kernel<<<dim3((M_TOT / GBM) * (ODIM / GBN)), dim3(512), GLDS, stream>>>(hb, Wb, bias, out);
  } else {
    fused_kernel<<<dim3(M_TOT / BM), dim3(NTHR), LDS_BYTES, stream>>>(
        x, lnw, lnb, W, bias, out);
  }
}